// Round 1
// baseline (332.271 us; speedup 1.0000x reference)
//
#include <hip/hip_runtime.h>
#include <math.h>

#define B_ 4
#define S_ 2048
#define E_ 1024
#define H_ 16
#define D_ 64
#define MRD 32

typedef __bf16 bf16x8 __attribute__((ext_vector_type(8)));
typedef float f32x4 __attribute__((ext_vector_type(4)));
typedef unsigned short us8 __attribute__((ext_vector_type(8)));
typedef unsigned short us4 __attribute__((ext_vector_type(4)));

union frag_cvt { us8 u; bf16x8 b; };
union h_cvt { __bf16 h; unsigned short u; };

__device__ __forceinline__ unsigned short bhi(float x) {
    h_cvt c; c.h = (__bf16)x; return c.u;
}
__device__ __forceinline__ float bf16_f(unsigned short h) {
    union { unsigned int u; float f; } c;
    c.u = ((unsigned int)h) << 16;
    return c.f;
}

__device__ __forceinline__ void async_copy16(const void* g, void* l) {
    __builtin_amdgcn_global_load_lds(
        (const __attribute__((address_space(1))) void*)g,
        (__attribute__((address_space(3))) void*)l,
        16, 0, 0);
}

__device__ __forceinline__ f32x4 mf16(const frag_cvt& a, const frag_cvt& b, f32x4 c) {
    return __builtin_amdgcn_mfma_f32_16x16x32_bf16(a.b, b.b, c, 0, 0, 0);
}

#define QSCL 0.18033688f    // 0.125 * log2(e) — folded into Qb at projection
#define L2E  1.44269504f

#define SBAR0() __builtin_amdgcn_sched_barrier(0)

// ---------------------------------------------------------------------------
// Convert pass: in[R][K] fp32 -> out[R][K] bf16, PLAIN row-major.
// (gemm8 computes its own stage-time swizzle from plain layout)
// ---------------------------------------------------------------------------
__global__ __launch_bounds__(128) void cvt_bf16(
    const float* __restrict__ in, unsigned short* __restrict__ out, int K)
{
    const int r  = blockIdx.x;
    const int k8 = threadIdx.x * 8;
    if (k8 >= K) return;
    const float* p = in + (size_t)r * K + k8;
    float4 a = *(const float4*)p;
    float4 b = *(const float4*)(p + 4);
    float xs[8] = {a.x, a.y, a.z, a.w, b.x, b.y, b.z, b.w};
    us8 hu;
#pragma unroll
    for (int j = 0; j < 8; ++j) hu[j] = bhi(xs[j]);
    *(us8*)&out[(size_t)r * K + k8] = hu;
}

// ---------------------------------------------------------------------------
// Split pass: in[R][K] fp32 -> out[R][2K] bf16 {hi | lo}, PLAIN.
// ---------------------------------------------------------------------------
__global__ __launch_bounds__(128) void split_hilo(
    const float* __restrict__ in, unsigned short* __restrict__ out, int K)
{
    const int r  = blockIdx.x;
    const int k8 = threadIdx.x * 8;
    if (k8 >= K) return;
    const float* p = in + (size_t)r * K + k8;
    float4 a = *(const float4*)p;
    float4 b = *(const float4*)(p + 4);
    float xs[8] = {a.x, a.y, a.z, a.w, b.x, b.y, b.z, b.w};
    us8 hu, lu;
#pragma unroll
    for (int j = 0; j < 8; ++j) {
        unsigned short hb = bhi(xs[j]);
        hu[j] = hb;
        lu[j] = bhi(xs[j] - bf16_f(hb));
    }
    *(us8*)&out[(size_t)r * 2 * K + k8]     = hu;
    *(us8*)&out[(size_t)r * 2 * K + K + k8] = lu;
}

// ---------------------------------------------------------------------------
// Stage one 128x64-bf16 unit (16 KB) into LDS via global_load_lds width 16.
// Global source is pre-swizzled (granule XOR with row&7) so that the linear
// LDS destination holds the swizzled layout the frag reads expect.
// g points at (row0)*grs + kk of a plain row-major bf16 matrix.
// lu is the unit's LDS base (ushort*). 512 threads, 2 loads each.
// ---------------------------------------------------------------------------
__device__ __forceinline__ void stage_unit(const unsigned short* g, int grs,
                                           unsigned short* lu, int t)
{
#pragma unroll
    for (int l = 0; l < 2; ++l) {
        const int f  = l * 512 + t;
        const int ri = f >> 3;                         // row in unit (0..127)
        const int cs = ((f & 7) ^ (ri & 7)) * 8;       // swizzled src col (elems)
        async_copy16(g + (size_t)ri * grs + cs,
                     lu + l * 4096 + (t >> 6) * 512);  // wave-uniform LDS base
    }
}

// ---------------------------------------------------------------------------
// 8-phase bf16 NT GEMM core (T2 swizzle + T3/T4 counted vmcnt + T5 setprio).
// BM=256, BN=128, BK=64, 512 threads = 8 waves (4M x 2N), wave tile 64x64.
// LDS: 2 buffers x (A 256x64 + B 128x64) = 96 KB.
// Per K-tile: 4 phases x 8 MFMA; stage units A1(k+1)@P1, B(k+2)@P3, A0(k+2)@P4;
// boundary s_waitcnt vmcnt(4) (2 units in flight), vmcnt(0) entering last tile.
//
// MODE 0: QKV projection. K=1024. Region epilogue -> Qb / K2 / Vt2.
// MODE 1: out projection, 3-term split via virtual K=3072 concat
//         A=[ah|ah|al] (stored [M][2048] = [hi|lo]), B=[bh|bl|bh]
//         (stored [N][2048] = [hi|lo]); pure source-offset remap.
// ---------------------------------------------------------------------------
template<int MODE>
__global__ __launch_bounds__(512, 2) void gemm8(
    const unsigned short* __restrict__ Ag, const unsigned short* __restrict__ Bg,
    const float* __restrict__ bias,
    unsigned short* __restrict__ O0, unsigned short* __restrict__ O1,
    unsigned short* __restrict__ O2, float* __restrict__ Cf)
{
    constexpr int KD = (MODE == 0) ? 1024 : 3072;  // logical K
    constexpr int NT = KD / 64;
    constexpr int AS = (MODE == 0) ? 1024 : 2048;  // A row stride (elems)
    constexpr int BS = (MODE == 0) ? 1024 : 2048;  // B row stride

    __shared__ unsigned short sbuf[2][24576];      // per buf: A@0 (16K us), B@16384 (8K us)

    const int t    = threadIdx.x;
    const int lane = t & 63;
    const int w    = t >> 6;
    const int ln   = lane & 15;
    const int quad = lane >> 4;
    const int wm   = w >> 1;       // 0..3
    const int wn   = w & 1;        // 0..1
    const int m0   = blockIdx.x * 256;
    const int n0   = blockIdx.y * 128;

    // logical K-offset -> source column in the stored [hi|lo] layout
    auto mapA = [](int kk) -> int {
        return (MODE == 0) ? kk : (kk < 1024 ? kk : kk - 1024);
    };
    auto mapB = [](int kk) -> int {
        return (MODE == 0) ? kk : (kk < 2048 ? kk : kk - 2048);
    };

    const int swz = (ln & 7) << 3;            // read-side granule swizzle (ushorts)
    const int kq0 = (quad * 8) ^ swz;         // ks=0 frag offset within row
    const int kq1 = (32 + quad * 8) ^ swz;    // ks=1

    f32x4 acc[4][4];
#pragma unroll
    for (int i = 0; i < 4; ++i)
#pragma unroll
        for (int j = 0; j < 4; ++j)
            acc[i][j] = (f32x4){0.f, 0.f, 0.f, 0.f};

    // ---- prologue: tile0 fully + {B(1), A0(1)} in flight -------------------
    stage_unit(Ag + (size_t)m0 * AS + mapA(0),         AS, &sbuf[0][0],     t); // A0(0)
    stage_unit(Ag + (size_t)(m0 + 128) * AS + mapA(0), AS, &sbuf[0][8192],  t); // A1(0)
    stage_unit(Bg + (size_t)n0 * BS + mapB(0),         BS, &sbuf[0][16384], t); // B(0)
    stage_unit(Bg + (size_t)n0 * BS + mapB(64),        BS, &sbuf[1][16384], t); // B(1)
    stage_unit(Ag + (size_t)m0 * AS + mapA(64),        AS, &sbuf[1][0],     t); // A0(1)
    asm volatile("s_waitcnt vmcnt(4)" ::: "memory");   // tile0 landed; 2 units in flight
    SBAR0();
    __builtin_amdgcn_s_barrier();
    SBAR0();

    for (int k = 0; k < NT; ++k) {
        unsigned short* bufc = sbuf[k & 1];
        unsigned short* bufn = sbuf[(k & 1) ^ 1];
        frag_cvt a0[2][2], a1[2][2], b0[2][2], b1[2][2];

        // ================= phase 1: read A-mh0 + B-nh0; stage A1(k+1) ======
#pragma unroll
        for (int i = 0; i < 2; ++i) {
            const int ra = (wm * 64 + i * 16 + ln) * 64;
            a0[i][0].u = *(const us8*)&bufc[ra + kq0];
            a0[i][1].u = *(const us8*)&bufc[ra + kq1];
            const int rb = 16384 + (wn * 64 + i * 16 + ln) * 64;
            b0[i][0].u = *(const us8*)&bufc[rb + kq0];
            b0[i][1].u = *(const us8*)&bufc[rb + kq1];
        }
        if (k + 1 < NT)
            stage_unit(Ag + (size_t)(m0 + 128) * AS + mapA((k + 1) * 64),
                       AS, &bufn[8192], t);
        SBAR0(); __builtin_amdgcn_s_barrier(); SBAR0();
        __builtin_amdgcn_s_setprio(1);
#pragma unroll
        for (int i = 0; i < 2; ++i)
#pragma unroll
            for (int j = 0; j < 2; ++j) {
                acc[i][j] = mf16(a0[i][0], b0[j][0], acc[i][j]);
                acc[i][j] = mf16(a0[i][1], b0[j][1], acc[i][j]);
            }
        __builtin_amdgcn_s_setprio(0);
        SBAR0(); __builtin_amdgcn_s_barrier(); SBAR0();

        // ================= phase 2: read B-nh1; mfma (mh0,nh1) =============
#pragma unroll
        for (int i = 0; i < 2; ++i) {
            const int rb = 16384 + (wn * 64 + (i + 2) * 16 + ln) * 64;
            b1[i][0].u = *(const us8*)&bufc[rb + kq0];
            b1[i][1].u = *(const us8*)&bufc[rb + kq1];
        }
        SBAR0(); __builtin_amdgcn_s_barrier(); SBAR0();
        __builtin_amdgcn_s_setprio(1);
#pragma unroll
        for (int i = 0; i < 2; ++i)
#pragma unroll
            for (int j = 0; j < 2; ++j) {
                acc[i][j + 2] = mf16(a0[i][0], b1[j][0], acc[i][j + 2]);
                acc[i][j + 2] = mf16(a0[i][1], b1[j][1], acc[i][j + 2]);
            }
        __builtin_amdgcn_s_setprio(0);
        SBAR0(); __builtin_amdgcn_s_barrier(); SBAR0();

        // ================= phase 3: read A-mh1; stage B(k+2); (mh1,nh1) ====
#pragma unroll
        for (int i = 0; i < 2; ++i) {
            const int ra = (wm * 64 + (i + 2) * 16 + ln) * 64;
            a1[i][0].u = *(const us8*)&bufc[ra + kq0];
            a1[i][1].u = *(const us8*)&bufc[ra + kq1];
        }
        if (k + 2 < NT)
            stage_unit(Bg + (size_t)n0 * BS + mapB((k + 2) * 64),
                       BS, &bufc[16384], t);
        SBAR0(); __builtin_amdgcn_s_barrier(); SBAR0();
        __builtin_amdgcn_s_setprio(1);
#pragma unroll
        for (int i = 0; i < 2; ++i)
#pragma unroll
            for (int j = 0; j < 2; ++j) {
                acc[i + 2][j + 2] = mf16(a1[i][0], b1[j][0], acc[i + 2][j + 2]);
                acc[i + 2][j + 2] = mf16(a1[i][1], b1[j][1], acc[i + 2][j + 2]);
            }
        __builtin_amdgcn_s_setprio(0);
        SBAR0(); __builtin_amdgcn_s_barrier(); SBAR0();

        // ================= phase 4: stage A0(k+2); (mh1,nh0); vmcnt ========
        if (k + 2 < NT)
            stage_unit(Ag + (size_t)m0 * AS + mapA((k + 2) * 64),
                       AS, &bufc[0], t);
        SBAR0(); __builtin_amdgcn_s_barrier(); SBAR0();
        __builtin_amdgcn_s_setprio(1);
#pragma unroll
        for (int i = 0; i < 2; ++i)
#pragma unroll
            for (int j = 0; j < 2; ++j) {
                acc[i + 2][j] = mf16(a1[i][0], b0[j][0], acc[i + 2][j]);
                acc[i + 2][j] = mf16(a1[i][1], b0[j][1], acc[i + 2][j]);
            }
        __builtin_amdgcn_s_setprio(0);
        if (k + 2 < NT) {
            asm volatile("s_waitcnt vmcnt(4)" ::: "memory");   // next tile landed
        } else if (k + 1 < NT) {
            asm volatile("s_waitcnt vmcnt(0)" ::: "memory");   // final drain
        }
        SBAR0(); __builtin_amdgcn_s_barrier(); SBAR0();
    }

    // ---- epilogue ----------------------------------------------------------
    if constexpr (MODE == 0) {
        if (n0 < E_) {
#pragma unroll
            for (int j = 0; j < 4; ++j) {
                const int col = n0 + wn * 64 + j * 16 + ln;
                const float bv = bias[col];
                const int h = (col & (E_ - 1)) >> 6, d = col & 63;
#pragma unroll
                for (int i = 0; i < 4; ++i) {
#pragma unroll
                    for (int r = 0; r < 4; ++r) {
                        const int row = m0 + wm * 64 + i * 16 + quad * 4 + r;
                        const int b = row >> 11, s = row & (S_ - 1);
                        O0[((size_t)(b * 16 + h) * S_ + s) * 64 + d] =
                            bhi((acc[i][j][r] + bv) * QSCL);
                    }
                }
            }
        } else if (n0 < 2 * E_) {
#pragma unroll
            for (int j = 0; j < 4; ++j) {
                const int col = n0 + wn * 64 + j * 16 + ln;
                const float bv = bias[col];
                const int h = (col & (E_ - 1)) >> 6, d = col & 63;
#pragma unroll
                for (int i = 0; i < 4; ++i) {
#pragma unroll
                    for (int r = 0; r < 4; ++r) {
                        const int row = m0 + wm * 64 + i * 16 + quad * 4 + r;
                        const int b = row >> 11, s = row & (S_ - 1);
                        O1[((size_t)(b * 16 + h) * S_ + s) * 64 +
                           (((d >> 3) ^ (s & 7)) * 8) + (d & 7)] =
                            bhi(acc[i][j][r] + bv);
                    }
                }
            }
        } else {
#pragma unroll
            for (int j = 0; j < 4; ++j) {
                const int col = n0 + wn * 64 + j * 16 + ln;
                const float bv = bias[col];
                const int h = (col & (E_ - 1)) >> 6, d = col & 63;
#pragma unroll
                for (int i = 0; i < 4; ++i) {
                    const int row0 = m0 + wm * 64 + i * 16 + quad * 4;
                    const int b = row0 >> 11, s0 = row0 & (S_ - 1);
                    const int tile = s0 >> 6;
                    const int g = (s0 >> 3) & 7;
                    us4 o;
#pragma unroll
                    for (int r = 0; r < 4; ++r) o[r] = bhi(acc[i][j][r] + bv);
                    *(us4*)&O2[(size_t)(b * 16 + h) * S_ * 64 + tile * 4096 +
                               d * 64 + ((g ^ (d & 7)) * 8) + (quad & 1) * 4] = o;
                }
            }
        }
    } else {
#pragma unroll
        for (int j = 0; j < 4; ++j) {
            const int col = n0 + wn * 64 + j * 16 + ln;
            const float bv = bias[col];
#pragma unroll
            for (int i = 0; i < 4; ++i) {
                const int row = m0 + wm * 64 + i * 16 + quad * 4;
#pragma unroll
                for (int r = 0; r < 4; ++r)
                    Cf[(size_t)(row + r) * E_ + col] = acc[i][j][r] + bv;
            }
        }
    }
}

// ---------------------------------------------------------------------------
// Flash attention v5 (unchanged structure): Q-tile 128, plain bf16, fp32
// accum, exp2-folded softmax. Epilogue now writes ctx2 PLAIN [M][2E]={hi|lo}.
// ---------------------------------------------------------------------------
__global__ __launch_bounds__(256, 4) void attn_mfma5(
    const unsigned short* __restrict__ Qb, const unsigned short* __restrict__ K2,
    const unsigned short* __restrict__ Vt2, const float* __restrict__ rel_bias,
    unsigned short* __restrict__ ctx2)
{
    __shared__ unsigned short Kt[64 * 64];    // 8 KB
    __shared__ unsigned short Vt[64 * 64];    // 8 KB
    __shared__ unsigned short Pt[128 * 72];   // 18 KB
    __shared__ float bias_s[65];

    const int t    = threadIdx.x;
    const int w    = t >> 6;
    const int lane = t & 63;
    const int ln   = lane & 15;
    const int quad = lane >> 4;

    const int bh = blockIdx.x;
    const int b  = bh >> 4;
    const int h  = bh & 15;
    const int q0 = blockIdx.y * 128;

    if (t < 65) {
        float s = 0.f;
#pragma unroll
        for (int hh = 0; hh < 16; ++hh) s += rel_bias[t * 16 + hh];
        bias_s[t] = s * (L2E / 16.f);
    }

    frag_cvt qf[2][2];
#pragma unroll
    for (int mf = 0; mf < 2; ++mf) {
        const unsigned short* qp =
            Qb + ((size_t)bh * S_ + q0 + w * 32 + mf * 16 + ln) * 64;
        qf[mf][0].u = *(const us8*)(qp + quad * 8);
        qf[mf][1].u = *(const us8*)(qp + 32 + quad * 8);
    }

    frag_cvt ones;
#pragma unroll
    for (int j = 0; j < 8; ++j) ones.u[j] = 0x3F80;

    f32x4 O[2][4];
#pragma unroll
    for (int mf = 0; mf < 2; ++mf)
#pragma unroll
        for (int n = 0; n < 4; ++n) O[mf][n] = (f32x4){0.f, 0.f, 0.f, 0.f};
    f32x4 lacc[2] = {(f32x4){0.f, 0.f, 0.f, 0.f}, (f32x4){0.f, 0.f, 0.f, 0.f}};

    const unsigned short* Kg = K2  + (size_t)bh * S_ * 64;
    const unsigned short* Vg = Vt2 + (size_t)bh * S_ * 64;

    for (int k0 = 0; k0 < S_; k0 += 64) {
        __syncthreads();
        {
            const unsigned short* kg = Kg + (size_t)k0 * 64;
            const unsigned short* vg = Vg + (size_t)k0 * 64;
            const int uo = w * 512;
            async_copy16(kg + uo + lane * 8,        &Kt[uo]);
            async_copy16(kg + 2048 + uo + lane * 8, &Kt[2048 + uo]);
            async_copy16(vg + uo + lane * 8,        &Vt[uo]);
            async_copy16(vg + 2048 + uo + lane * 8, &Vt[2048 + uo]);
        }
        __syncthreads();

        f32x4 sa[2][4];
#pragma unroll
        for (int n = 0; n < 4; ++n) {
            sa[0][n] = (f32x4){0.f, 0.f, 0.f, 0.f};
            sa[1][n] = (f32x4){0.f, 0.f, 0.f, 0.f};
            const int ro = (n * 16 + ln) * 64;
#pragma unroll
            for (int ks = 0; ks < 2; ++ks) {
                frag_cvt kh;
                kh.u = *(const us8*)&Kt[ro + (((ks * 4 + quad) ^ (ln & 7)) * 8)];
                sa[0][n] = __builtin_amdgcn_mfma_f32_16x16x32_bf16(
                    qf[0][ks].b, kh.b, sa[0][n], 0, 0, 0);
                sa[1][n] = __builtin_amdgcn_mfma_f32_16x16x32_bf16(
                    qf[1][ks].b, kh.b, sa[1][n], 0, 0, 0);
            }
        }

        const bool inband = (k0 >= q0 - 64) && (k0 <= q0 + 128);
        float cb = 0.f;
        if (!inband) cb = bias_s[(k0 < q0) ? 64 : 0];
#pragma unroll
        for (int mf = 0; mf < 2; ++mf) {
#pragma unroll
            for (int n = 0; n < 4; ++n) {
#pragma unroll
                for (int r = 0; r < 4; ++r) {
                    float s2;
                    if (inband) {
                        const int q   = q0 + w * 32 + mf * 16 + quad * 4 + r;
                        const int key = k0 + n * 16 + ln;
                        int rel = q - key;
                        rel = (rel < -MRD) ? -MRD : (rel > MRD ? MRD : rel);
                        s2 = sa[mf][n][r] + bias_s[rel + MRD];
                    } else {
                        s2 = sa[mf][n][r] + cb;
                    }
                    const int qrow = w * 32 + mf * 16 + quad * 4 + r;
                    const int pos = (n * 16 + ln) ^ ((qrow & 8) << 1);
                    Pt[qrow * 72 + pos] = bhi(__builtin_amdgcn_exp2f(s2));
                }
            }
        }

#pragma unroll
        for (int ks = 0; ks < 2; ++ks) {
            frag_cvt pa[2];
#pragma unroll
            for (int mf = 0; mf < 2; ++mf) {
                const int prow = w * 32 + mf * 16 + ln;
                pa[mf].u = *(const us8*)&Pt[prow * 72 +
                           ((ks * 32 + quad * 8) ^ ((prow & 8) << 1))];
                lacc[mf] = __builtin_amdgcn_mfma_f32_16x16x32_bf16(
                    pa[mf].b, ones.b, lacc[mf], 0, 0, 0);
            }
#pragma unroll
            for (int n = 0; n < 4; ++n) {
                frag_cvt vh;
                vh.u = *(const us8*)&Vt[(n * 16 + ln) * 64 +
                                        (((ks * 4 + quad) ^ (ln & 7)) * 8)];
                O[0][n] = __builtin_amdgcn_mfma_f32_16x16x32_bf16(
                    pa[0].b, vh.b, O[0][n], 0, 0, 0);
                O[1][n] = __builtin_amdgcn_mfma_f32_16x16x32_bf16(
                    pa[1].b, vh.b, O[1][n], 0, 0, 0);
            }
        }
    }

#pragma unroll
    for (int mf = 0; mf < 2; ++mf) {
        float inv[4];
#pragma unroll
        for (int r = 0; r < 4; ++r) inv[r] = 1.f / lacc[mf][r];
#pragma unroll
        for (int n = 0; n < 4; ++n) {
            const int k = h * D_ + n * 16 + ln;
#pragma unroll
            for (int r = 0; r < 4; ++r) {
                const int q = q0 + w * 32 + mf * 16 + quad * 4 + r;
                const float v = O[mf][n][r] * inv[r];
                unsigned short hb = bhi(v);
                const size_t rb = (size_t)(b * S_ + q) * (2 * E_);
                ctx2[rb + k]      = hb;
                ctx2[rb + E_ + k] = bhi(v - bf16_f(hb));
            }
        }
    }
}

// ---------------------------------------------------------------------------
extern "C" void kernel_launch(void* const* d_in, const int* in_sizes, int n_in,
                              void* d_out, int out_size, void* d_ws, size_t ws_size,
                              hipStream_t stream)
{
    const float* x         = (const float*)d_in[0];
    const float* in_proj_w = (const float*)d_in[1];
    const float* in_proj_b = (const float*)d_in[2];
    const float* out_w     = (const float*)d_in[3];
    const float* out_b     = (const float*)d_in[4];
    const float* rel_bias  = (const float*)d_in[5];
    float* out = (float*)d_out;

    const int M = B_ * S_;                         // 8192
    const size_t PH = (size_t)B_ * H_ * S_ * 64;   // 8.39M ushorts

    // workspace (~94 MB):
    //   Qb, K2, Vt2: 3 x 16.8 MB
    //   W2o [E][2E]: 4.2 MB; Wqkv [3E][E]: 6.3 MB
    //   A2c [M][2E]: 33.6 MB (also hosts Axb [M][E] — disjoint lifetimes)
    unsigned short* Qb   = (unsigned short*)d_ws;
    unsigned short* K2   = Qb + PH;
    unsigned short* Vt2  = K2 + PH;
    unsigned short* W2o  = Vt2 + PH;
    unsigned short* Wqkv = W2o + (size_t)E_ * 2 * E_;
    unsigned short* A2c  = Wqkv + (size_t)3 * E_ * E_;
    unsigned short* Axb  = A2c;   // overlap: Axb dead before attn writes A2c

    // 1) convert x and in_proj_w to plain bf16
    cvt_bf16<<<M,      128, 0, stream>>>(x,         Axb,  E_);
    cvt_bf16<<<3 * E_, 128, 0, stream>>>(in_proj_w, Wqkv, E_);

    // 2) QKV projection (8-phase core) -> Qb (pre-scaled) / K2 / Vt2
    {
        dim3 grid(M / 256, (3 * E_) / 128);   // 32 x 24 = 768 blocks
        gemm8<0><<<grid, 512, 0, stream>>>(Axb, Wqkv, in_proj_b,
                                           Qb, K2, Vt2, nullptr);
    }
    // 3) attention -> A2c (plain [hi|lo])
    {
        dim3 grid(B_ * H_, S_ / 128);
        attn_mfma5<<<grid, 256, 0, stream>>>(Qb, K2, Vt2, rel_bias, A2c);
    }
    // 4) split out_w, 3-term output projection (8-phase core, virtual K=3072)
    split_hilo<<<E_, 128, 0, stream>>>(out_w, W2o, E_);
    {
        dim3 grid(M / 256, E_ / 128);         // 32 x 8 = 256 blocks
        gemm8<1><<<grid, 512, 0, stream>>>(A2c, W2o, out_b,
                                           nullptr, nullptr, nullptr, out);
    }
}

// Round 2
// 325.980 us; speedup vs baseline: 1.0193x; 1.0193x over previous
//
#include <hip/hip_runtime.h>
#include <math.h>

#define B_ 4
#define S_ 2048
#define E_ 1024
#define H_ 16
#define D_ 64
#define MRD 32

typedef __bf16 bf16x8 __attribute__((ext_vector_type(8)));
typedef float f32x4 __attribute__((ext_vector_type(4)));
typedef unsigned short us8 __attribute__((ext_vector_type(8)));
typedef unsigned short us4 __attribute__((ext_vector_type(4)));

union frag_cvt { us8 u; bf16x8 b; };
union h_cvt { __bf16 h; unsigned short u; };

__device__ __forceinline__ unsigned short bhi(float x) {
    h_cvt c; c.h = (__bf16)x; return c.u;
}
__device__ __forceinline__ float bf16_f(unsigned short h) {
    union { unsigned int u; float f; } c;
    c.u = ((unsigned int)h) << 16;
    return c.f;
}

__device__ __forceinline__ void async_copy16(const void* g, void* l) {
    __builtin_amdgcn_global_load_lds(
        (const __attribute__((address_space(1))) void*)g,
        (__attribute__((address_space(3))) void*)l,
        16, 0, 0);
}

__device__ __forceinline__ f32x4 mf16(const frag_cvt& a, const frag_cvt& b, f32x4 c) {
    return __builtin_amdgcn_mfma_f32_16x16x32_bf16(a.b, b.b, c, 0, 0, 0);
}

#define QSCL 0.18033688f    // 0.125 * log2(e) — folded into Qb at projection
#define L2E  1.44269504f

// ---------------------------------------------------------------------------
// Convert pass: in[R][K] fp32 -> out[R][K] bf16, PLAIN row-major.
// ---------------------------------------------------------------------------
__global__ __launch_bounds__(128) void cvt_bf16(
    const float* __restrict__ in, unsigned short* __restrict__ out, int K)
{
    const int r  = blockIdx.x;
    const int k8 = threadIdx.x * 8;
    if (k8 >= K) return;
    const float* p = in + (size_t)r * K + k8;
    float4 a = *(const float4*)p;
    float4 b = *(const float4*)(p + 4);
    float xs[8] = {a.x, a.y, a.z, a.w, b.x, b.y, b.z, b.w};
    us8 hu;
#pragma unroll
    for (int j = 0; j < 8; ++j) hu[j] = bhi(xs[j]);
    *(us8*)&out[(size_t)r * K + k8] = hu;
}

// ---------------------------------------------------------------------------
// Split pass: in[R][K] fp32 -> out[R][2K] bf16 {hi | lo}, PLAIN.
// ---------------------------------------------------------------------------
__global__ __launch_bounds__(128) void split_hilo(
    const float* __restrict__ in, unsigned short* __restrict__ out, int K)
{
    const int r  = blockIdx.x;
    const int k8 = threadIdx.x * 8;
    if (k8 >= K) return;
    const float* p = in + (size_t)r * K + k8;
    float4 a = *(const float4*)p;
    float4 b = *(const float4*)(p + 4);
    float xs[8] = {a.x, a.y, a.z, a.w, b.x, b.y, b.z, b.w};
    us8 hu, lu;
#pragma unroll
    for (int j = 0; j < 8; ++j) {
        unsigned short hb = bhi(xs[j]);
        hu[j] = hb;
        lu[j] = bhi(xs[j] - bf16_f(hb));
    }
    *(us8*)&out[(size_t)r * 2 * K + k8]     = hu;
    *(us8*)&out[(size_t)r * 2 * K + K + k8] = lu;
}

// ---------------------------------------------------------------------------
// Stage one 128x64-bf16 unit (16 KB) into LDS via global_load_lds width 16.
// Global source is pre-swizzled (granule XOR with row&7) so that the linear
// LDS destination holds the swizzled layout the frag reads expect.
// ---------------------------------------------------------------------------
__device__ __forceinline__ void stage_unit(const unsigned short* g, int grs,
                                           unsigned short* lu, int t)
{
#pragma unroll
    for (int l = 0; l < 2; ++l) {
        const int f  = l * 512 + t;
        const int ri = f >> 3;                         // row in unit (0..127)
        const int cs = ((f & 7) ^ (ri & 7)) * 8;       // swizzled src col (elems)
        async_copy16(g + (size_t)ri * grs + cs,
                     lu + l * 4096 + (t >> 6) * 512);  // wave-uniform LDS base
    }
}

// ---------------------------------------------------------------------------
// bf16 NT GEMM core, 2-barrier counted-vmcnt structure:
//   per K-tile: { free section: 16 ds_read_b128 + 32 MFMA (compiler-
//   scheduled, setprio around MFMA) ; s_barrier ; stage 3 units of tile
//   k+2 ; s_waitcnt vmcnt(6) ; s_barrier }.
// BM=256, BN=128, BK=64, 512 threads = 8 waves (4M x 2N), wave tile 64x64.
// LDS: 2 buffers x (A 256x64 + B 128x64) = 96 KB -> 1 block/CU, 2 waves/SIMD.
// Raw s_barrier (not __syncthreads) avoids the compiler's vmcnt(0) drain;
// every staged unit has >= 1 full K-tile of flight before its vmcnt check.
//
// MODE 0: QKV projection. K=1024. Region epilogue -> Qb / K2 / Vt2.
// MODE 1: out projection, 3-term split via virtual K=3072 concat
//         A=[ah|ah|al] (stored [M][2048] = [hi|lo]), B=[bh|bl|bh]
//         (stored [N][2048] = [hi|lo]); pure source-offset remap.
// ---------------------------------------------------------------------------
template<int MODE>
__global__ __launch_bounds__(512, 2) void gemm8(
    const unsigned short* __restrict__ Ag, const unsigned short* __restrict__ Bg,
    const float* __restrict__ bias,
    unsigned short* __restrict__ O0, unsigned short* __restrict__ O1,
    unsigned short* __restrict__ O2, float* __restrict__ Cf)
{
    constexpr int KD = (MODE == 0) ? 1024 : 3072;  // logical K
    constexpr int NT = KD / 64;
    constexpr int AS = (MODE == 0) ? 1024 : 2048;  // A row stride (elems)
    constexpr int BS = (MODE == 0) ? 1024 : 2048;  // B row stride

    __shared__ unsigned short sbuf[2][24576];      // per buf: A@0 (16K us), B@16384 (8K us)

    const int t    = threadIdx.x;
    const int lane = t & 63;
    const int w    = t >> 6;
    const int ln   = lane & 15;
    const int quad = lane >> 4;
    const int wm   = w >> 1;       // 0..3
    const int wn   = w & 1;        // 0..1
    const int m0   = blockIdx.x * 256;
    const int n0   = blockIdx.y * 128;

    // logical K-offset -> source column in the stored [hi|lo] layout
    auto mapA = [](int kk) -> int {
        return (MODE == 0) ? kk : (kk < 1024 ? kk : kk - 1024);
    };
    auto mapB = [](int kk) -> int {
        return (MODE == 0) ? kk : (kk < 2048 ? kk : kk - 2048);
    };

    const int swz = (ln & 7) << 3;            // read-side granule swizzle (ushorts)
    const int kq0 = (quad * 8) ^ swz;         // ks=0 frag offset within row
    const int kq1 = (32 + quad * 8) ^ swz;    // ks=1

    f32x4 acc[4][4];
#pragma unroll
    for (int i = 0; i < 4; ++i)
#pragma unroll
        for (int j = 0; j < 4; ++j)
            acc[i][j] = (f32x4){0.f, 0.f, 0.f, 0.f};

    // ---- prologue: stage tiles 0 and 1 (12 loads/thread), wait tile 0 -----
    stage_unit(Ag + (size_t)m0 * AS + mapA(0),          AS, &sbuf[0][0],     t);
    stage_unit(Ag + (size_t)(m0 + 128) * AS + mapA(0),  AS, &sbuf[0][8192],  t);
    stage_unit(Bg + (size_t)n0 * BS + mapB(0),          BS, &sbuf[0][16384], t);
    stage_unit(Ag + (size_t)m0 * AS + mapA(64),         AS, &sbuf[1][0],     t);
    stage_unit(Ag + (size_t)(m0 + 128) * AS + mapA(64), AS, &sbuf[1][8192],  t);
    stage_unit(Bg + (size_t)n0 * BS + mapB(64),         BS, &sbuf[1][16384], t);
    asm volatile("s_waitcnt vmcnt(6)" ::: "memory");   // tile 0 landed
    __builtin_amdgcn_s_barrier();

    for (int k = 0; k < NT; ++k) {
        unsigned short* bufc = sbuf[k & 1];
        frag_cvt af[4][2], bg[4][2];

        // ---- free compute section: reads + MFMA, no barriers inside ------
#pragma unroll
        for (int i = 0; i < 4; ++i) {
            const int ra = (wm * 64 + i * 16 + ln) * 64;
            af[i][0].u = *(const us8*)&bufc[ra + kq0];
            af[i][1].u = *(const us8*)&bufc[ra + kq1];
            const int rb = 16384 + (wn * 64 + i * 16 + ln) * 64;
            bg[i][0].u = *(const us8*)&bufc[rb + kq0];
            bg[i][1].u = *(const us8*)&bufc[rb + kq1];
        }
        __builtin_amdgcn_s_setprio(1);
#pragma unroll
        for (int i = 0; i < 4; ++i)
#pragma unroll
            for (int j = 0; j < 4; ++j) {
                acc[i][j] = mf16(af[i][0], bg[j][0], acc[i][j]);
                acc[i][j] = mf16(af[i][1], bg[j][1], acc[i][j]);
            }
        __builtin_amdgcn_s_setprio(0);

        if (k == NT - 1) break;

        // ---- barrier 1: all reads of bufc complete block-wide ------------
        __builtin_amdgcn_s_barrier();

        // ---- stage tile k+2 into bufc (freed), counted vmcnt -------------
        if (k + 2 < NT) {
            const int kk = (k + 2) * 64;
            stage_unit(Ag + (size_t)m0 * AS + mapA(kk),         AS, &bufc[0],     t);
            stage_unit(Ag + (size_t)(m0 + 128) * AS + mapA(kk), AS, &bufc[8192],  t);
            stage_unit(Bg + (size_t)n0 * BS + mapB(kk),         BS, &bufc[16384], t);
            asm volatile("s_waitcnt vmcnt(6)" ::: "memory");   // tile k+1 landed
        } else {
            asm volatile("s_waitcnt vmcnt(0)" ::: "memory");   // final drain
        }

        // ---- barrier 2: tile k+1 visible to all waves --------------------
        __builtin_amdgcn_s_barrier();
    }

    // ---- epilogue ----------------------------------------------------------
    if constexpr (MODE == 0) {
        if (n0 < E_) {
#pragma unroll
            for (int j = 0; j < 4; ++j) {
                const int col = n0 + wn * 64 + j * 16 + ln;
                const float bv = bias[col];
                const int h = (col & (E_ - 1)) >> 6, d = col & 63;
#pragma unroll
                for (int i = 0; i < 4; ++i) {
#pragma unroll
                    for (int r = 0; r < 4; ++r) {
                        const int row = m0 + wm * 64 + i * 16 + quad * 4 + r;
                        const int b = row >> 11, s = row & (S_ - 1);
                        O0[((size_t)(b * 16 + h) * S_ + s) * 64 + d] =
                            bhi((acc[i][j][r] + bv) * QSCL);
                    }
                }
            }
        } else if (n0 < 2 * E_) {
#pragma unroll
            for (int j = 0; j < 4; ++j) {
                const int col = n0 + wn * 64 + j * 16 + ln;
                const float bv = bias[col];
                const int h = (col & (E_ - 1)) >> 6, d = col & 63;
#pragma unroll
                for (int i = 0; i < 4; ++i) {
#pragma unroll
                    for (int r = 0; r < 4; ++r) {
                        const int row = m0 + wm * 64 + i * 16 + quad * 4 + r;
                        const int b = row >> 11, s = row & (S_ - 1);
                        O1[((size_t)(b * 16 + h) * S_ + s) * 64 +
                           (((d >> 3) ^ (s & 7)) * 8) + (d & 7)] =
                            bhi(acc[i][j][r] + bv);
                    }
                }
            }
        } else {
#pragma unroll
            for (int j = 0; j < 4; ++j) {
                const int col = n0 + wn * 64 + j * 16 + ln;
                const float bv = bias[col];
                const int h = (col & (E_ - 1)) >> 6, d = col & 63;
#pragma unroll
                for (int i = 0; i < 4; ++i) {
                    const int row0 = m0 + wm * 64 + i * 16 + quad * 4;
                    const int b = row0 >> 11, s0 = row0 & (S_ - 1);
                    const int tile = s0 >> 6;
                    const int g = (s0 >> 3) & 7;
                    us4 o;
#pragma unroll
                    for (int r = 0; r < 4; ++r) o[r] = bhi(acc[i][j][r] + bv);
                    *(us4*)&O2[(size_t)(b * 16 + h) * S_ * 64 + tile * 4096 +
                               d * 64 + ((g ^ (d & 7)) * 8) + (quad & 1) * 4] = o;
                }
            }
        }
    } else {
#pragma unroll
        for (int j = 0; j < 4; ++j) {
            const int col = n0 + wn * 64 + j * 16 + ln;
            const float bv = bias[col];
#pragma unroll
            for (int i = 0; i < 4; ++i) {
                const int row = m0 + wm * 64 + i * 16 + quad * 4;
#pragma unroll
                for (int r = 0; r < 4; ++r)
                    Cf[(size_t)(row + r) * E_ + col] = acc[i][j][r] + bv;
            }
        }
    }
}

// ---------------------------------------------------------------------------
// Flash attention v5 (unchanged): Q-tile 128, plain bf16, fp32 accum,
// exp2-folded softmax. Epilogue writes ctx2 PLAIN [M][2E]={hi|lo}.
// ---------------------------------------------------------------------------
__global__ __launch_bounds__(256, 4) void attn_mfma5(
    const unsigned short* __restrict__ Qb, const unsigned short* __restrict__ K2,
    const unsigned short* __restrict__ Vt2, const float* __restrict__ rel_bias,
    unsigned short* __restrict__ ctx2)
{
    __shared__ unsigned short Kt[64 * 64];    // 8 KB
    __shared__ unsigned short Vt[64 * 64];    // 8 KB
    __shared__ unsigned short Pt[128 * 72];   // 18 KB
    __shared__ float bias_s[65];

    const int t    = threadIdx.x;
    const int w    = t >> 6;
    const int lane = t & 63;
    const int ln   = lane & 15;
    const int quad = lane >> 4;

    const int bh = blockIdx.x;
    const int b  = bh >> 4;
    const int h  = bh & 15;
    const int q0 = blockIdx.y * 128;

    if (t < 65) {
        float s = 0.f;
#pragma unroll
        for (int hh = 0; hh < 16; ++hh) s += rel_bias[t * 16 + hh];
        bias_s[t] = s * (L2E / 16.f);
    }

    frag_cvt qf[2][2];
#pragma unroll
    for (int mf = 0; mf < 2; ++mf) {
        const unsigned short* qp =
            Qb + ((size_t)bh * S_ + q0 + w * 32 + mf * 16 + ln) * 64;
        qf[mf][0].u = *(const us8*)(qp + quad * 8);
        qf[mf][1].u = *(const us8*)(qp + 32 + quad * 8);
    }

    frag_cvt ones;
#pragma unroll
    for (int j = 0; j < 8; ++j) ones.u[j] = 0x3F80;

    f32x4 O[2][4];
#pragma unroll
    for (int mf = 0; mf < 2; ++mf)
#pragma unroll
        for (int n = 0; n < 4; ++n) O[mf][n] = (f32x4){0.f, 0.f, 0.f, 0.f};
    f32x4 lacc[2] = {(f32x4){0.f, 0.f, 0.f, 0.f}, (f32x4){0.f, 0.f, 0.f, 0.f}};

    const unsigned short* Kg = K2  + (size_t)bh * S_ * 64;
    const unsigned short* Vg = Vt2 + (size_t)bh * S_ * 64;

    for (int k0 = 0; k0 < S_; k0 += 64) {
        __syncthreads();
        {
            const unsigned short* kg = Kg + (size_t)k0 * 64;
            const unsigned short* vg = Vg + (size_t)k0 * 64;
            const int uo = w * 512;
            async_copy16(kg + uo + lane * 8,        &Kt[uo]);
            async_copy16(kg + 2048 + uo + lane * 8, &Kt[2048 + uo]);
            async_copy16(vg + uo + lane * 8,        &Vt[uo]);
            async_copy16(vg + 2048 + uo + lane * 8, &Vt[2048 + uo]);
        }
        __syncthreads();

        f32x4 sa[2][4];
#pragma unroll
        for (int n = 0; n < 4; ++n) {
            sa[0][n] = (f32x4){0.f, 0.f, 0.f, 0.f};
            sa[1][n] = (f32x4){0.f, 0.f, 0.f, 0.f};
            const int ro = (n * 16 + ln) * 64;
#pragma unroll
            for (int ks = 0; ks < 2; ++ks) {
                frag_cvt kh;
                kh.u = *(const us8*)&Kt[ro + (((ks * 4 + quad) ^ (ln & 7)) * 8)];
                sa[0][n] = __builtin_amdgcn_mfma_f32_16x16x32_bf16(
                    qf[0][ks].b, kh.b, sa[0][n], 0, 0, 0);
                sa[1][n] = __builtin_amdgcn_mfma_f32_16x16x32_bf16(
                    qf[1][ks].b, kh.b, sa[1][n], 0, 0, 0);
            }
        }

        const bool inband = (k0 >= q0 - 64) && (k0 <= q0 + 128);
        float cb = 0.f;
        if (!inband) cb = bias_s[(k0 < q0) ? 64 : 0];
#pragma unroll
        for (int mf = 0; mf < 2; ++mf) {
#pragma unroll
            for (int n = 0; n < 4; ++n) {
#pragma unroll
                for (int r = 0; r < 4; ++r) {
                    float s2;
                    if (inband) {
                        const int q   = q0 + w * 32 + mf * 16 + quad * 4 + r;
                        const int key = k0 + n * 16 + ln;
                        int rel = q - key;
                        rel = (rel < -MRD) ? -MRD : (rel > MRD ? MRD : rel);
                        s2 = sa[mf][n][r] + bias_s[rel + MRD];
                    } else {
                        s2 = sa[mf][n][r] + cb;
                    }
                    const int qrow = w * 32 + mf * 16 + quad * 4 + r;
                    const int pos = (n * 16 + ln) ^ ((qrow & 8) << 1);
                    Pt[qrow * 72 + pos] = bhi(__builtin_amdgcn_exp2f(s2));
                }
            }
        }

#pragma unroll
        for (int ks = 0; ks < 2; ++ks) {
            frag_cvt pa[2];
#pragma unroll
            for (int mf = 0; mf < 2; ++mf) {
                const int prow = w * 32 + mf * 16 + ln;
                pa[mf].u = *(const us8*)&Pt[prow * 72 +
                           ((ks * 32 + quad * 8) ^ ((prow & 8) << 1))];
                lacc[mf] = __builtin_amdgcn_mfma_f32_16x16x32_bf16(
                    pa[mf].b, ones.b, lacc[mf], 0, 0, 0);
            }
#pragma unroll
            for (int n = 0; n < 4; ++n) {
                frag_cvt vh;
                vh.u = *(const us8*)&Vt[(n * 16 + ln) * 64 +
                                        (((ks * 4 + quad) ^ (ln & 7)) * 8)];
                O[0][n] = __builtin_amdgcn_mfma_f32_16x16x32_bf16(
                    pa[0].b, vh.b, O[0][n], 0, 0, 0);
                O[1][n] = __builtin_amdgcn_mfma_f32_16x16x32_bf16(
                    pa[1].b, vh.b, O[1][n], 0, 0, 0);
            }
        }
    }

#pragma unroll
    for (int mf = 0; mf < 2; ++mf) {
        float inv[4];
#pragma unroll
        for (int r = 0; r < 4; ++r) inv[r] = 1.f / lacc[mf][r];
#pragma unroll
        for (int n = 0; n < 4; ++n) {
            const int k = h * D_ + n * 16 + ln;
#pragma unroll
            for (int r = 0; r < 4; ++r) {
                const int q = q0 + w * 32 + mf * 16 + quad * 4 + r;
                const float v = O[mf][n][r] * inv[r];
                unsigned short hb = bhi(v);
                const size_t rb = (size_t)(b * S_ + q) * (2 * E_);
                ctx2[rb + k]      = hb;
                ctx2[rb + E_ + k] = bhi(v - bf16_f(hb));
            }
        }
    }
}

// ---------------------------------------------------------------------------
extern "C" void kernel_launch(void* const* d_in, const int* in_sizes, int n_in,
                              void* d_out, int out_size, void* d_ws, size_t ws_size,
                              hipStream_t stream)
{
    const float* x         = (const float*)d_in[0];
    const float* in_proj_w = (const float*)d_in[1];
    const float* in_proj_b = (const float*)d_in[2];
    const float* out_w     = (const float*)d_in[3];
    const float* out_b     = (const float*)d_in[4];
    const float* rel_bias  = (const float*)d_in[5];
    float* out = (float*)d_out;

    const int M = B_ * S_;                         // 8192
    const size_t PH = (size_t)B_ * H_ * S_ * 64;   // 8.39M ushorts

    unsigned short* Qb   = (unsigned short*)d_ws;
    unsigned short* K2   = Qb + PH;
    unsigned short* Vt2  = K2 + PH;
    unsigned short* W2o  = Vt2 + PH;
    unsigned short* Wqkv = W2o + (size_t)E_ * 2 * E_;
    unsigned short* A2c  = Wqkv + (size_t)3 * E_ * E_;
    unsigned short* Axb  = A2c;   // overlap: Axb dead before attn writes A2c

    // 1) convert x and in_proj_w to plain bf16
    cvt_bf16<<<M,      128, 0, stream>>>(x,         Axb,  E_);
    cvt_bf16<<<3 * E_, 128, 0, stream>>>(in_proj_w, Wqkv, E_);

    // 2) QKV projection (2-barrier counted-vmcnt core) -> Qb / K2 / Vt2
    {
        dim3 grid(M / 256, (3 * E_) / 128);   // 32 x 24 = 768 blocks
        gemm8<0><<<grid, 512, 0, stream>>>(Axb, Wqkv, in_proj_b,
                                           Qb, K2, Vt2, nullptr);
    }
    // 3) attention -> A2c (plain [hi|lo])
    {
        dim3 grid(B_ * H_, S_ / 128);
        attn_mfma5<<<grid, 256, 0, stream>>>(Qb, K2, Vt2, rel_bias, A2c);
    }
    // 4) split out_w, 3-term output projection (virtual K=3072)
    split_hilo<<<E_, 128, 0, stream>>>(out_w, W2o, E_);
    {
        dim3 grid(M / 256, E_ / 128);         // 32 x 8 = 256 blocks
        gemm8<1><<<grid, 512, 0, stream>>>(A2c, W2o, out_b,
                                           nullptr, nullptr, nullptr, out);
    }
}